// Round 2
// baseline (657.929 us; speedup 1.0000x reference)
//
#include <hip/hip_runtime.h>

// Problem constants
#define TOTAL_DIM 24976   // 400 + 60*256 + 36*256
#define N_ROWS    97      // 1 + 60 + 36
#define D_MODEL   512
#define EPSLN     1e-5f

// grid decomposition: 32 output rows per workgroup (main path)
#define NB0 64
#define NB1 3840
#define NB2 2304

// Wt (bf16, transposed, k-padded) layout in d_ws:
//  split0: [512][416] at elem 0        (212992 elems)
//  split1: [512][256] at elem 212992   (131072 elems)
//  split2: [512][256] at elem 344064   (131072 elems)
#define WT_TOTAL 475136
#define WT_BYTES (WT_TOTAL * 2)

typedef __attribute__((ext_vector_type(8))) short frag8;   // 8 bf16 = 4 VGPRs
typedef __attribute__((ext_vector_type(4))) float frag4;   // 4 fp32 acc

__device__ __forceinline__ unsigned short f2b(float f) {
  // fp32 -> bf16 round-to-nearest-even
  unsigned u = __float_as_uint(f);
  u = u + 0x7fffu + ((u >> 16) & 1u);
  return (unsigned short)(u >> 16);
}

__device__ __forceinline__ void async_copy16(const void* g, void* l) {
  // 16B per lane, LDS dest = wave-uniform base + lane*16 (HW rule)
  __builtin_amdgcn_global_load_lds(
      (const __attribute__((address_space(1))) void*)g,
      (__attribute__((address_space(3))) void*)l, 16, 0, 0);
}

// ---------------- prep: W fp32 [l][512] -> bf16 W^T [512][KP] (zero pad k>=l) ----
__global__ void __launch_bounds__(256) prep_wt(const float* __restrict__ W0,
                                               const float* __restrict__ W1,
                                               const float* __restrict__ W2,
                                               unsigned short* __restrict__ wt) {
  int i = blockIdx.x * 256 + threadIdx.x;
  if (i < 212992) {                       // 512*416
    int n = i / 416, kp = i - n * 416;
    float v = (kp < 400) ? W0[kp * 512 + n] : 0.f;
    wt[i] = f2b(v);
  } else if (i < 344064) {                // +512*256
    int j = i - 212992;
    int n = j >> 8, kp = j & 255;
    wt[i] = f2b(W1[kp * 512 + n]);
  } else if (i < WT_TOTAL) {
    int j = i - 344064;
    int n = j >> 8, kp = j & 255;
    wt[i] = f2b(W2[kp * 512 + n]);
  }
}

// ---------------- fused GEMM + bias + ReLU + LayerNorm (MFMA main path) ----------
// one workgroup = 32 rows x 512 cols (full N -> LN is workgroup-local)
// wave w covers cols [w*128, w*128+128) as 8 n-tiles; 2 m-tiles of 16 rows
// LDS: Blds 32KB (swizzled chunks) | Alds 32x40 bf16 (pad 40 keeps 16B align,
//      breaks conflicts) | red 4*32*2 f32 | stat 32*2 f32  -> 36608 B dynamic
template <int S>
__device__ __forceinline__ void run_split(
    int blk, char* smem,
    const float* __restrict__ x, const unsigned short* __restrict__ wt,
    const float* __restrict__ bias, const float* __restrict__ gam,
    const float* __restrict__ bet, float* __restrict__ out) {
  constexpr int L     = (S == 0) ? 400 : 256;       // true K
  constexpr int KP    = (S == 0) ? 416 : 256;       // padded K (mult of 32)
  constexpr int START = (S == 0) ? 0 : (S == 1) ? 400 : 15760;
  constexpr int KK    = (S == 0) ? 1 : (S == 1) ? 60 : 36;   // slices
  constexpr int OFF   = (S == 0) ? 0 : (S == 1) ? 1 : 61;    // row offset in output
  constexpr int WTO   = (S == 0) ? 0 : (S == 1) ? 212992 : 344064;
  constexpr int NSTEP = KP / 32;

  unsigned short* Blds = (unsigned short*)smem;             // 16384 bf16
  unsigned short* Alds = (unsigned short*)(smem + 32768);   // 32 x 40 bf16
  float* red  = (float*)(smem + 35328);                     // [4][32][2]
  float* stat = (float*)(smem + 36352);                     // [32][2]

  const int tid  = threadIdx.x;
  const int lane = tid & 63, wave = tid >> 6;
  const int q = lane >> 4, c = lane & 15;
  const int m_base = blk * 32;

  // ---- A staging setup: thread loads row (tid>>3), k-quad (tid&7)*4
  const int arow = tid >> 3;
  const int akq  = (tid & 7) * 4;
  const float* aptr;
  {
    int m = m_base + arow;
    int bb = m / KK, jj = m - bb * KK;
    aptr = x + (size_t)bb * TOTAL_DIM + START + jj * L + akq;
  }

  // ---- B staging setup: 2048 chunks of 16B; swizzle s(n)=(n>>1)&3 on k-chunk.
  // LDS linear position p holds (n=p>>2, kchunk=(p&3)^s(n)) -> gather absorbs swizzle.
  const unsigned short* bptr[8];
  unsigned short* bdst[8];
#pragma unroll
  for (int r = 0; r < 8; ++r) {
    int p = r * 256 + tid;
    int n = p >> 2;
    int kc = ((p & 3) ^ ((n >> 1) & 3)) * 8;
    bptr[r] = wt + WTO + n * KP + kc;
    bdst[r] = Blds + (size_t)(r * 256 + wave * 64) * 8;  // wave-uniform base
  }

  // ---- fragment LDS offsets (constant over K loop)
  const int a_off0 = (c) * 40 + q * 8;
  const int a_off1 = (16 + c) * 40 + q * 8;
  int b_off[8];
#pragma unroll
  for (int nt = 0; nt < 8; ++nt) {
    int n = wave * 128 + nt * 16 + c;
    b_off[nt] = (n * 4 + (q ^ ((n >> 1) & 3))) * 8;
  }

  frag4 acc[2][8];
#pragma unroll
  for (int mt = 0; mt < 2; ++mt)
#pragma unroll
    for (int nt = 0; nt < 8; ++nt) {
      frag4 z = {0.f, 0.f, 0.f, 0.f};
      acc[mt][nt] = z;
    }

  // ---- K loop
  for (int t = 0; t < NSTEP; ++t) {
#pragma unroll
    for (int r = 0; r < 8; ++r) async_copy16(bptr[r], bdst[r]);

    float4 av;
    const float* p = aptr + t * 32;
    if (S == 0) {  // K=400 not mult of 32: predicated tail -> zeros
      int k = t * 32 + akq;
      av.x = (k + 0 < L) ? p[0] : 0.f;
      av.y = (k + 1 < L) ? p[1] : 0.f;
      av.z = (k + 2 < L) ? p[2] : 0.f;
      av.w = (k + 3 < L) ? p[3] : 0.f;
    } else {
      av = *(const float4*)p;
    }
    unsigned lo = (unsigned)f2b(av.x) | ((unsigned)f2b(av.y) << 16);
    unsigned hi = (unsigned)f2b(av.z) | ((unsigned)f2b(av.w) << 16);
    *(uint2*)(Alds + arow * 40 + akq) = make_uint2(lo, hi);

#pragma unroll
    for (int r = 0; r < 8; ++r) bptr[r] += 32;  // next 32-k slab

    __syncthreads();  // drains vmcnt (global_load_lds) + lgkm before compute

    frag8 a0 = *(const frag8*)(Alds + a_off0);
    frag8 a1 = *(const frag8*)(Alds + a_off1);
#pragma unroll
    for (int nt = 0; nt < 8; ++nt) {
      frag8 bf = *(const frag8*)(Blds + b_off[nt]);
      acc[0][nt] = __builtin_amdgcn_mfma_f32_16x16x32_bf16(a0, bf, acc[0][nt], 0, 0, 0);
      acc[1][nt] = __builtin_amdgcn_mfma_f32_16x16x32_bf16(a1, bf, acc[1][nt], 0, 0, 0);
    }
    __syncthreads();  // reads done before next stage overwrites
  }

  // ---- epilogue: bias + ReLU + LayerNorm, all from registers
  const int colbase = wave * 128 + c;
  float bv[8], gv[8], ev[8];
#pragma unroll
  for (int nt = 0; nt < 8; ++nt) {
    int col = colbase + nt * 16;
    bv[nt] = bias[col];
    gv[nt] = gam[col];
    ev[nt] = bet[col];
  }

  // C/D layout: col = lane&15 (c), row = q*4 + reg  [m89-verified]
#pragma unroll
  for (int mt = 0; mt < 2; ++mt) {
    float s[4] = {0.f, 0.f, 0.f, 0.f}, s2[4] = {0.f, 0.f, 0.f, 0.f};
#pragma unroll
    for (int nt = 0; nt < 8; ++nt)
#pragma unroll
      for (int r = 0; r < 4; ++r) {
        float h = acc[mt][nt][r] + bv[nt];
        h = fmaxf(h, 0.f);
        acc[mt][nt][r] = h;
        s[r] += h;
        s2[r] += h * h;
      }
#pragma unroll
    for (int r = 0; r < 4; ++r) {
      float a = s[r], b2 = s2[r];
#pragma unroll
      for (int msk = 1; msk < 16; msk <<= 1) {  // reduce across 16 cols (same q)
        a += __shfl_xor(a, msk, 64);
        b2 += __shfl_xor(b2, msk, 64);
      }
      if (c == 0) {
        int row = mt * 16 + q * 4 + r;
        red[(wave * 32 + row) * 2 + 0] = a;
        red[(wave * 32 + row) * 2 + 1] = b2;
      }
    }
  }
  __syncthreads();
  if (tid < 32) {
    float s = 0.f, s2 = 0.f;
#pragma unroll
    for (int w = 0; w < 4; ++w) {
      s  += red[(w * 32 + tid) * 2 + 0];
      s2 += red[(w * 32 + tid) * 2 + 1];
    }
    float mu  = s * (1.f / 512.f);
    float var = s2 * (1.f / 512.f) - mu * mu;
    stat[tid * 2 + 0] = mu;
    stat[tid * 2 + 1] = rsqrtf(var + EPSLN);
  }
  __syncthreads();

#pragma unroll
  for (int mt = 0; mt < 2; ++mt)
#pragma unroll
    for (int r = 0; r < 4; ++r) {
      int row = mt * 16 + q * 4 + r;
      float mu = stat[row * 2 + 0], sc = stat[row * 2 + 1];
      int m = m_base + row;
      int bb = m / KK, jj = m - bb * KK;   // const divisor -> magic mul
      size_t orow = (size_t)bb * N_ROWS + OFF + jj;
      float* op = out + orow * D_MODEL + colbase;
#pragma unroll
      for (int nt = 0; nt < 8; ++nt)
        op[nt * 16] = (acc[mt][nt][r] - mu) * sc * gv[nt] + ev[nt];
    }
}

__global__ void __launch_bounds__(256, 2) fused_kernel(
    const float* __restrict__ x, const unsigned short* __restrict__ wt,
    const float* __restrict__ b0, const float* __restrict__ g0, const float* __restrict__ e0,
    const float* __restrict__ b1, const float* __restrict__ g1, const float* __restrict__ e1,
    const float* __restrict__ b2, const float* __restrict__ g2, const float* __restrict__ e2,
    float* __restrict__ out) {
  extern __shared__ char smem[];
  int bid = blockIdx.x;
  if (bid < NB0)
    run_split<0>(bid, smem, x, wt, b0, g0, e0, out);
  else if (bid < NB0 + NB1)
    run_split<1>(bid - NB0, smem, x, wt, b1, g1, e1, out);
  else
    run_split<2>(bid - NB0 - NB1, smem, x, wt, b2, g2, e2, out);
}

// ---------------- fallback: fp32 vector path, zero workspace ---------------------
// one block = one output row. Correct-but-slow; only used if ws_size is too small.
template <int S>
__global__ void __launch_bounds__(256) fallback_split(
    const float* __restrict__ x, const float* __restrict__ W,
    const float* __restrict__ bias, const float* __restrict__ gam,
    const float* __restrict__ bet, float* __restrict__ out) {
  constexpr int L     = (S == 0) ? 400 : 256;
  constexpr int START = (S == 0) ? 0 : (S == 1) ? 400 : 15760;
  constexpr int KK    = (S == 0) ? 1 : (S == 1) ? 60 : 36;
  constexpr int OFF   = (S == 0) ? 0 : (S == 1) ? 1 : 61;

  __shared__ float xs[400];
  __shared__ float rs[4], rs2[4];

  int m = blockIdx.x;
  int bb = m / KK, jj = m - bb * KK;
  const float* xp = x + (size_t)bb * TOTAL_DIM + START + jj * L;
  for (int k = threadIdx.x; k < L; k += 256) xs[k] = xp[k];
  __syncthreads();

  float h[2];
#pragma unroll
  for (int i = 0; i < 2; ++i) {
    int col = threadIdx.x + i * 256;
    float acc = 0.f;
    for (int k = 0; k < L; ++k) acc += xs[k] * W[k * 512 + col];
    h[i] = fmaxf(acc + bias[col], 0.f);
  }

  float s = h[0] + h[1], s2 = h[0] * h[0] + h[1] * h[1];
#pragma unroll
  for (int msk = 1; msk < 64; msk <<= 1) {
    s  += __shfl_xor(s, msk, 64);
    s2 += __shfl_xor(s2, msk, 64);
  }
  int wave = threadIdx.x >> 6, lane = threadIdx.x & 63;
  if (lane == 0) { rs[wave] = s; rs2[wave] = s2; }
  __syncthreads();
  s  = rs[0] + rs[1] + rs[2] + rs[3];
  s2 = rs2[0] + rs2[1] + rs2[2] + rs2[3];
  float mu  = s * (1.f / 512.f);
  float var = s2 * (1.f / 512.f) - mu * mu;
  float sc  = rsqrtf(var + EPSLN);

  float* op = out + ((size_t)bb * N_ROWS + OFF + jj) * D_MODEL;
#pragma unroll
  for (int i = 0; i < 2; ++i) {
    int col = threadIdx.x + i * 256;
    op[col] = (h[i] - mu) * sc * gam[col] + bet[col];
  }
}

extern "C" void kernel_launch(void* const* d_in, const int* in_sizes, int n_in,
                              void* d_out, int out_size, void* d_ws, size_t ws_size,
                              hipStream_t stream) {
  const float* x  = (const float*)d_in[0];
  const float* W0 = (const float*)d_in[1];
  const float* b0 = (const float*)d_in[2];
  const float* g0 = (const float*)d_in[3];
  const float* e0 = (const float*)d_in[4];
  const float* W1 = (const float*)d_in[5];
  const float* b1 = (const float*)d_in[6];
  const float* g1 = (const float*)d_in[7];
  const float* e1 = (const float*)d_in[8];
  const float* W2 = (const float*)d_in[9];
  const float* b2 = (const float*)d_in[10];
  const float* g2 = (const float*)d_in[11];
  const float* e2 = (const float*)d_in[12];
  float* out = (float*)d_out;

  if (ws_size >= (size_t)WT_BYTES) {
    // fast path: bf16 MFMA, fused GEMM+bias+ReLU+LN
    unsigned short* wt = (unsigned short*)d_ws;
    prep_wt<<<(WT_TOTAL + 255) / 256, 256, 0, stream>>>(W0, W1, W2, wt);
    fused_kernel<<<NB0 + NB1 + NB2, 256, 36608, stream>>>(
        x, wt, b0, g0, e0, b1, g1, e1, b2, g2, e2, out);
  } else {
    // zero-workspace fp32 fallback (correct, slower)
    fallback_split<0><<<2048,   256, 0, stream>>>(x, W0, b0, g0, e0, out);
    fallback_split<1><<<122880, 256, 0, stream>>>(x, W1, b1, g1, e1, out);
    fallback_split<2><<<73728,  256, 0, stream>>>(x, W2, b2, g2, e2, out);
  }
}